// Round 12
// baseline (208.564 us; speedup 1.0000x reference)
//
#include <hip/hip_runtime.h>
#include <hip/hip_bf16.h>

// Problem constants
#define BB 8
#define TT 4096
#define FF 256
#define BT 32768   // BB*TT

typedef unsigned short u16;
typedef __attribute__((ext_vector_type(8))) short short8;
typedef __attribute__((ext_vector_type(4))) float f32x4;
typedef __attribute__((ext_vector_type(4))) unsigned int u32x4;

static __device__ __forceinline__ float bf2f(u16 u) {
    union { unsigned int i; float f; } v; v.i = ((unsigned int)u) << 16; return v.f;
}
static __device__ __forceinline__ u16 f2bf(float f) {
    union { float f; unsigned int i; } v; v.f = f;
    unsigned int x = v.i;
    return (u16)((x + 0x7fffu + ((x >> 16) & 1u)) >> 16);  // RNE
}

typedef const __attribute__((address_space(1))) void gvoid_t;
typedef __attribute__((address_space(3))) void svoid_t;

// ---------------------------------------------------------------------------
// exp_w: exp(w) -> bf16 [T][T]. Row-max dropped: it is constant over the
// einsum's summation index s, so it scales num and den identically and
// cancels exactly in num/den. |w| <= ~0.1 so exp(w) ~ 1 (no overflow).
// ---------------------------------------------------------------------------
__global__ __launch_bounds__(256) void expw_kernel(const float* __restrict__ w,
                                                   u16* __restrict__ ew) {
    int row = blockIdx.x;
    int tid = threadIdx.x;
    const float* wr = w + (size_t)row * TT;
#pragma unroll
    for (int v = 0; v < 4; ++v) {
        int idx = (v * 256 + tid) * 4;
        f32x4 vals = *(const f32x4*)(wr + idx);
        float e0 = expf(vals[0]), e1 = expf(vals[1]);
        float e2 = expf(vals[2]), e3 = expf(vals[3]);
        uint2 pk;
        pk.x = (unsigned int)f2bf(e0) | ((unsigned int)f2bf(e1) << 16);
        pk.y = (unsigned int)f2bf(e2) | ((unsigned int)f2bf(e3) << 16);
        *(uint2*)(ew + (size_t)row * TT + idx) = pk;
    }
}

// ---------------------------------------------------------------------------
// merged casts: x -> xbf (f32x4 chunks), wq->wqb, wo->wob, (wk,wv)->wkv
// ---------------------------------------------------------------------------
__global__ __launch_bounds__(256) void cvt_all_kernel(const float* __restrict__ x,
                                                      const float* __restrict__ wq,
                                                      const float* __restrict__ wo,
                                                      const float* __restrict__ wk,
                                                      const float* __restrict__ wv,
                                                      u16* __restrict__ xbf,
                                                      u16* __restrict__ wqb,
                                                      u16* __restrict__ wob,
                                                      u16* __restrict__ wkv) {
    int i = blockIdx.x * 256 + threadIdx.x;
    if (i < 2097152) {
        int idx = i * 4;
        f32x4 v = *(const f32x4*)(x + idx);
        uint2 pk;
        pk.x = (unsigned int)f2bf(v[0]) | ((unsigned int)f2bf(v[1]) << 16);
        pk.y = (unsigned int)f2bf(v[2]) | ((unsigned int)f2bf(v[3]) << 16);
        *(uint2*)(xbf + idx) = pk;
        return;
    }
    int j = i - 2097152;           // [0, 49152)
    int which = j >> 14, k = j & 16383;
    int idx = k * 4;
    if (which == 0) {
        f32x4 v = *(const f32x4*)(wq + idx);
        uint2 pk;
        pk.x = (unsigned int)f2bf(v[0]) | ((unsigned int)f2bf(v[1]) << 16);
        pk.y = (unsigned int)f2bf(v[2]) | ((unsigned int)f2bf(v[3]) << 16);
        *(uint2*)(wqb + idx) = pk;
    } else if (which == 1) {
        f32x4 v = *(const f32x4*)(wo + idx);
        uint2 pk;
        pk.x = (unsigned int)f2bf(v[0]) | ((unsigned int)f2bf(v[1]) << 16);
        pk.y = (unsigned int)f2bf(v[2]) | ((unsigned int)f2bf(v[3]) << 16);
        *(uint2*)(wob + idx) = pk;
    } else {
        int f = idx >> 8, c = idx & 255;
        f32x4 a = *(const f32x4*)(wk + idx);
        f32x4 b = *(const f32x4*)(wv + idx);
        uint2 pa, pb;
        pa.x = (unsigned int)f2bf(a[0]) | ((unsigned int)f2bf(a[1]) << 16);
        pa.y = (unsigned int)f2bf(a[2]) | ((unsigned int)f2bf(a[3]) << 16);
        pb.x = (unsigned int)f2bf(b[0]) | ((unsigned int)f2bf(b[1]) << 16);
        pb.y = (unsigned int)f2bf(b[2]) | ((unsigned int)f2bf(b[3]) << 16);
        *(uint2*)(wkv + (size_t)(2 * f) * 256 + c) = pa;
        *(uint2*)(wkv + (size_t)(2 * f + 1) * 256 + c) = pb;
    }
}

// ---------------------------------------------------------------------------
// Small NT GEMM (m97 structure) + 64B-row XOR swizzle (R11-verified).
// MODE 0: f32 out; 1: sigmoid->bf16
// ---------------------------------------------------------------------------
template <int MODE>
__global__ __launch_bounds__(256) void gemm_nt(const u16* __restrict__ A,
                                               const u16* __restrict__ Bm,
                                               const float* __restrict__ bias,
                                               void* __restrict__ Call,
                                               int M, int N, int K) {
    __shared__ u16 As[128 * 32];
    __shared__ u16 Bs[128 * 32];

    int tid = threadIdx.x;
    int lane = tid & 63;
    int w = tid >> 6;
    int wr = w >> 1, wc = w & 1;
    int fr = lane & 15, kg = lane >> 4;

    f32x4 acc[4][4];
#pragma unroll
    for (int m = 0; m < 4; ++m)
#pragma unroll
        for (int n = 0; n < 4; ++n) acc[m][n] = (f32x4){0.f, 0.f, 0.f, 0.f};

    int bm = blockIdx.x, bn = blockIdx.y;
    int nk = K >> 5;

    int srow = tid >> 2;
    int schunk = ((tid & 3) ^ ((tid >> 3) & 3)) << 3;   // inverse-swizzled source col
    const u16* aBase = A + (size_t)(bm * 128 + srow) * K + schunk;
    const u16* bBase = Bm + (size_t)(bn * 128 + srow) * K + schunk;
    size_t half = (size_t)64 * K;

    int xsw = (kg * 8) ^ (((fr >> 1) & 3) << 3);        // swizzled read col (elems)

    for (int kt = 0; kt < nk; ++kt) {
        __syncthreads();
        int ko = kt << 5;
        __builtin_amdgcn_global_load_lds((gvoid_t*)(aBase + ko), (svoid_t*)&As[tid * 8], 16, 0, 0);
        __builtin_amdgcn_global_load_lds((gvoid_t*)(aBase + half + ko), (svoid_t*)&As[2048 + tid * 8], 16, 0, 0);
        __builtin_amdgcn_global_load_lds((gvoid_t*)(bBase + ko), (svoid_t*)&Bs[tid * 8], 16, 0, 0);
        __builtin_amdgcn_global_load_lds((gvoid_t*)(bBase + half + ko), (svoid_t*)&Bs[2048 + tid * 8], 16, 0, 0);
        __syncthreads();

        short8 af[4], bfr[4];
#pragma unroll
        for (int m = 0; m < 4; ++m)
            af[m] = *(const short8*)&As[(wr * 64 + m * 16 + fr) * 32 + xsw];
#pragma unroll
        for (int n = 0; n < 4; ++n)
            bfr[n] = *(const short8*)&Bs[(wc * 64 + n * 16 + fr) * 32 + xsw];
#pragma unroll
        for (int m = 0; m < 4; ++m)
#pragma unroll
            for (int n = 0; n < 4; ++n)
                acc[m][n] = __builtin_amdgcn_mfma_f32_16x16x32_bf16(af[m], bfr[n], acc[m][n], 0, 0, 0);
    }

    int row0 = bm * 128 + wr * 64;
    int col0 = bn * 128 + wc * 64;
#pragma unroll
    for (int n = 0; n < 4; ++n) {
        int col = col0 + n * 16 + fr;
        float bv = bias ? bias[col] : 0.0f;
#pragma unroll
        for (int m = 0; m < 4; ++m) {
            int rbase = row0 + m * 16 + kg * 4;
#pragma unroll
            for (int i = 0; i < 4; ++i) {
                float val = acc[m][n][i] + bv;
                size_t idx = (size_t)(rbase + i) * N + col;
                if (MODE == 0)
                    ((float*)Call)[idx] = val;
                else
                    ((u16*)Call)[idx] = f2bf(1.0f / (1.0f + expf(-val)));
            }
        }
    }
}

// ---------------------------------------------------------------------------
// Fused K/V projection + Mt build (R11, unchanged — feature-dim max REQUIRED:
// it varies over the summation index s and does not cancel in num/den).
// ---------------------------------------------------------------------------
__global__ __launch_bounds__(512) void kv_mt_kernel(const u16* __restrict__ xbf,
                                                    const u16* __restrict__ wkv,
                                                    const float* __restrict__ bk,
                                                    const float* __restrict__ bv,
                                                    u16* __restrict__ mt) {
    __shared__ u16 As[128 * 32];     // 8 KB
    __shared__ u16 Bs[512 * 32];     // 32 KB
    __shared__ float rmax4[128][4];  // 2 KB

    int tid = threadIdx.x;
    int lane = tid & 63, wid = tid >> 6;
    int fr = lane & 15, kg = lane >> 4;
    int wr = wid >> 2, wc = wid & 3;
    int row0g = blockIdx.x * 128;

    f32x4 acc[4][8];
#pragma unroll
    for (int m = 0; m < 4; ++m)
#pragma unroll
        for (int n = 0; n < 8; ++n) acc[m][n] = (f32x4){0.f, 0.f, 0.f, 0.f};

    int scol = ((tid & 3) ^ ((tid >> 3) & 3)) << 3;   // inverse-swizzled source col
    const u16* aSrc = xbf + (size_t)(row0g + (tid >> 2)) * 256 + scol;
    const u16* bSrc = wkv + (size_t)(tid >> 2) * 256 + scol;
    int xsw = (kg * 8) ^ (((fr >> 1) & 3) << 3);      // swizzled read col (elems)

    for (int ks = 0; ks < 8; ++ks) {
        __syncthreads();
        __builtin_amdgcn_global_load_lds((gvoid_t*)(aSrc + ks * 32), (svoid_t*)&As[tid * 8], 16, 0, 0);
#pragma unroll
        for (int c = 0; c < 4; ++c)
            __builtin_amdgcn_global_load_lds((gvoid_t*)(bSrc + (size_t)c * 128 * 256 + ks * 32),
                                             (svoid_t*)&Bs[c * 4096 + tid * 8], 16, 0, 0);
        __syncthreads();

        short8 af[4], bfr[8];
#pragma unroll
        for (int m = 0; m < 4; ++m)
            af[m] = *(const short8*)&As[(wr * 64 + m * 16 + fr) * 32 + xsw];
#pragma unroll
        for (int n = 0; n < 8; ++n)
            bfr[n] = *(const short8*)&Bs[(wc * 128 + n * 16 + fr) * 32 + xsw];
#pragma unroll
        for (int m = 0; m < 4; ++m)
#pragma unroll
            for (int n = 0; n < 8; ++n)
                acc[m][n] = __builtin_amdgcn_mfma_f32_16x16x32_bf16(af[m], bfr[n], acc[m][n], 0, 0, 0);
    }

    int par = fr & 1;   // 0: K (den), 1: V (num)
#pragma unroll
    for (int n = 0; n < 8; ++n) {
        int col = wc * 128 + n * 16 + fr;
        int f = col >> 1;
        float bvv = par ? bv[f] : bk[f];
#pragma unroll
        for (int m = 0; m < 4; ++m)
#pragma unroll
            for (int i = 0; i < 4; ++i) acc[m][n][i] += bvv;
    }

    float rmax[4][4];
#pragma unroll
    for (int m = 0; m < 4; ++m)
#pragma unroll
        for (int i = 0; i < 4; ++i) {
            float mx = -1e30f;
#pragma unroll
            for (int n = 0; n < 8; ++n) mx = fmaxf(mx, par ? -1e30f : acc[m][n][i]);
            mx = fmaxf(mx, __shfl_xor(mx, 2));
            mx = fmaxf(mx, __shfl_xor(mx, 4));
            mx = fmaxf(mx, __shfl_xor(mx, 8));
            mx = fmaxf(mx, __shfl_xor(mx, 1));
            rmax[m][i] = mx;
        }
    if (fr == 0) {
#pragma unroll
        for (int m = 0; m < 4; ++m)
#pragma unroll
            for (int i = 0; i < 4; ++i)
                rmax4[wr * 64 + m * 16 + kg * 4 + i][wc] = rmax[m][i];
    }
    __syncthreads();
#pragma unroll
    for (int m = 0; m < 4; ++m)
#pragma unroll
        for (int i = 0; i < 4; ++i) {
            f32x4 r4 = *(const f32x4*)rmax4[wr * 64 + m * 16 + kg * 4 + i];
            rmax[m][i] = fmaxf(fmaxf(r4[0], r4[1]), fmaxf(r4[2], r4[3]));
        }

    int b = row0g >> 12;
    int tcb = (row0g & 4095) + wr * 64;
#pragma unroll
    for (int n = 0; n < 8; ++n) {
        int col = wc * 128 + n * 16 + fr;
        int f = col >> 1;
        size_t rowmt = (size_t)(b * 512 + 2 * f + (par ? 0 : 1));
#pragma unroll
        for (int m = 0; m < 4; ++m) {
            int tc = tcb + m * 16 + kg * 4;
            u16 o[4];
#pragma unroll
            for (int i = 0; i < 4; ++i) {
                float v = acc[m][n][i];
                float ek = expf(v - rmax[m][i]);
                float ekx = __shfl_xor(ek, 1);
                float outv = par ? (ekx * v) : ek;
                o[i] = f2bf(outv);
            }
            uint2 pk;
            pk.x = (unsigned int)o[0] | ((unsigned int)o[1] << 16);
            pk.y = (unsigned int)o[2] | ((unsigned int)o[3] << 16);
            *(uint2*)(mt + rowmt * TT + tc) = pk;
        }
    }
}

// ---------------------------------------------------------------------------
// Big GEMM, occupancy experiment: tile 256x128, BK=32, 2 LDS bufs (48 KB)
// -> 2 blocks/CU (512 blocks, launch_bounds(512,4)). R6-exact sync skeleton:
// per tile {reads | stage next | lgkm(0) | MFMA half1 | reads half2 | lgkm(0)
// | MFMA half2 | vmcnt(0) | bar}. 64B-row XOR swizzle (R11-verified
// involution: phys_chunk = log_chunk ^ ((row>>1)&3); 2 lanes/bank = free).
// Fused all-lane AFT epilogue.
// ---------------------------------------------------------------------------
#define GLDS(src, eoff) \
    __builtin_amdgcn_global_load_lds((gvoid_t*)(src), (svoid_t*)&L[eoff], 16, 0, 0)

#define STAGE3(P_, KS_) do {                                                   \
    GLDS(sA + (KS_) * 32, (P_) * 8192 + dst);                                  \
    GLDS(sA + (size_t)128 * 4096 + (KS_) * 32, (P_) * 8192 + 4096 + dst);      \
    GLDS(sB + (KS_) * 32, 16384 + (P_) * 4096 + dst);                          \
} while (0)

__global__ __launch_bounds__(512, 4) void gemm256_nt(const u16* __restrict__ A,
                                                     const u16* __restrict__ B,
                                                     const u16* __restrict__ qsig,
                                                     u16* __restrict__ yt) {
    __shared__ u16 L[24576];   // 48 KiB: A bufs [0,16384) elems, B bufs [16384,24576)
    const int K = 4096;
    int tid = threadIdx.x;
    int lane = tid & 63, wid = tid >> 6;
    int fr = lane & 15, kg = lane >> 4;
    int wr = wid >> 2, wc = wid & 3;    // 2 x 4 waves
    int bm = blockIdx.x, bn = blockIdx.y;   // 16 x 32

    // swizzled read col (elems) + row bases (rows are 32 elems = 64 B)
    int xsw = (kg * 8) ^ (((fr >> 1) & 3) << 3);
    int arow = (wr * 128 + fr) * 32;   // + mf*512
    int brow = (wc * 32 + fr) * 32;    // + nf*512

    // staging source (inverse swizzle); dest = linear tid*16B per issue
    int scol = ((tid & 3) ^ ((tid >> 3) & 3)) << 3;
    const u16* sA = A + (size_t)(bm * 256 + (tid >> 2)) * K + scol;
    const u16* sB = B + (size_t)(bn * 128 + (tid >> 2)) * K + scol;
    int dst = tid * 8;   // elems

    f32x4 acc[8][2];
#pragma unroll
    for (int m = 0; m < 8; ++m)
#pragma unroll
        for (int n = 0; n < 2; ++n) acc[m][n] = (f32x4){0.f, 0.f, 0.f, 0.f};

    // prologue: stage tile 0 -> buf 0
    STAGE3(0, 0);
    asm volatile("s_waitcnt vmcnt(0)" ::: "memory");
    __builtin_amdgcn_sched_barrier(0);
    __builtin_amdgcn_s_barrier();

#pragma unroll 1
    for (int t = 0; t < 128; ++t) {
        int p = t & 1;
        int Ab = p * 8192;
        int Bb = 16384 + p * 4096;

        short8 af[4], bfr[2];
#pragma unroll
        for (int nf = 0; nf < 2; ++nf)
            bfr[nf] = *(const short8*)&L[Bb + brow + nf * 512 + xsw];
#pragma unroll
        for (int mf = 0; mf < 4; ++mf)
            af[mf] = *(const short8*)&L[Ab + arow + mf * 512 + xsw];
        int ks = (t + 1 < 128) ? t + 1 : 0;
        STAGE3(p ^ 1, ks);
        asm volatile("s_waitcnt lgkmcnt(0)" ::: "memory");
        __builtin_amdgcn_sched_barrier(0);
        __builtin_amdgcn_s_setprio(1);
#pragma unroll
        for (int mf = 0; mf < 4; ++mf)
#pragma unroll
            for (int nf = 0; nf < 2; ++nf)
                acc[mf][nf] = __builtin_amdgcn_mfma_f32_16x16x32_bf16(af[mf], bfr[nf], acc[mf][nf], 0, 0, 0);
        __builtin_amdgcn_s_setprio(0);
        // second half: m rows 4..7
#pragma unroll
        for (int mf = 0; mf < 4; ++mf)
            af[mf] = *(const short8*)&L[Ab + arow + (mf + 4) * 512 + xsw];
        asm volatile("s_waitcnt lgkmcnt(0)" ::: "memory");
        __builtin_amdgcn_sched_barrier(0);
        __builtin_amdgcn_s_setprio(1);
#pragma unroll
        for (int mf = 0; mf < 4; ++mf)
#pragma unroll
            for (int nf = 0; nf < 2; ++nf)
                acc[mf + 4][nf] = __builtin_amdgcn_mfma_f32_16x16x32_bf16(af[mf], bfr[nf], acc[mf + 4][nf], 0, 0, 0);
        __builtin_amdgcn_s_setprio(0);
        asm volatile("s_waitcnt vmcnt(0)" ::: "memory");
        __builtin_amdgcn_sched_barrier(0);
        __builtin_amdgcn_s_barrier();
    }

    // fused AFT epilogue: all lanes productive. Even fr: i 0..1; odd fr: i 2..3.
    int colgb = bn * 128 + wc * 32;
    int row0 = bm * 256 + wr * 128;
    int par = fr & 1;
#pragma unroll
    for (int n = 0; n < 2; ++n) {
        int colg = colgb + n * 16 + fr;
        int b = colg >> 9;
        int f = (colg & 511) >> 1;
#pragma unroll
        for (int m = 0; m < 8; ++m) {
            int tr0 = row0 + m * 16 + kg * 4;
            float v0 = acc[m][n][0], v1 = acc[m][n][1];
            float v2 = acc[m][n][2], v3 = acc[m][n][3];
            float o0 = __shfl_xor(v0, 1), o1 = __shfl_xor(v1, 1);
            float o2 = __shfl_xor(v2, 1), o3 = __shfl_xor(v3, 1);
            float nA = par ? o2 : v0, dA = par ? v2 : o0;   // i = par?2:0
            float nB = par ? o3 : v1, dB = par ? v3 : o1;   // i = par?3:1
            int iA = par ? 2 : 0;
            size_t idxA = ((size_t)(b * 4096 + tr0 + iA) << 8) + f;
            size_t idxB = idxA + 256;
            float qA = bf2f(qsig[idxA]);
            float qB = bf2f(qsig[idxB]);
            yt[idxA] = f2bf(qA * nA * __builtin_amdgcn_rcpf(dA));
            yt[idxB] = f2bf(qB * nB * __builtin_amdgcn_rcpf(dB));
        }
    }
}

// ---------------------------------------------------------------------------
extern "C" void kernel_launch(void* const* d_in, const int* in_sizes, int n_in,
                              void* d_out, int out_size, void* d_ws, size_t ws_size,
                              hipStream_t stream) {
    const float* x  = (const float*)d_in[0];
    const float* wq = (const float*)d_in[1];
    const float* bq = (const float*)d_in[2];
    const float* wk = (const float*)d_in[3];
    const float* bk = (const float*)d_in[4];
    const float* wv = (const float*)d_in[5];
    const float* bv = (const float*)d_in[6];
    const float* w  = (const float*)d_in[7];
    const float* wo = (const float*)d_in[8];
    const float* bo = (const float*)d_in[9];

    char* p = (char*)d_ws;
    u16* expw = (u16*)p; p += (size_t)TT * TT * 2;        // 32 MiB
    u16* xbf  = (u16*)p; p += (size_t)BT * FF * 2;        // 16 MiB (reused as yt)
    u16* wqb  = (u16*)p; p += (size_t)FF * FF * 2;
    u16* wob  = (u16*)p; p += (size_t)FF * FF * 2;
    u16* wkv  = (u16*)p; p += (size_t)2 * FF * FF * 2;    // interleaved [512][256]
    u16* qsig = (u16*)p; p += (size_t)BT * FF * 2;        // 16 MiB
    u16* mt   = (u16*)p; p += (size_t)BB * 512 * TT * 2;  // 32 MiB (flat [4096][T])
    u16* yt = xbf;

    expw_kernel<<<TT, 256, 0, stream>>>(w, expw);

    // merged casts: 2097152 (x) + 49152 (weights) work items
    cvt_all_kernel<<<8384, 256, 0, stream>>>(x, wq, wo, wk, wv, xbf, wqb, wob, wkv);

    dim3 gp(BT / 128, FF / 128, 1);
    gemm_nt<1><<<gp, 256, 0, stream>>>(xbf, wqb, bq, qsig, BT, FF, FF);

    kv_mt_kernel<<<BT / 128, 512, 0, stream>>>(xbf, wkv, bk, bv, mt);

    // big GEMM + fused AFT epilogue: 256x128 tiles, 512 blocks (2/CU)
    gemm256_nt<<<dim3(16, 32), 512, 0, stream>>>(expw, mt, qsig, yt);

    gemm_nt<0><<<gp, 256, 0, stream>>>(yt, wob, bo, (float*)d_out, BT, FF, FF);
}

// Round 13
// 185.677 us; speedup vs baseline: 1.1233x; 1.1233x over previous
//
#include <hip/hip_runtime.h>
#include <hip/hip_bf16.h>

// Problem constants
#define BB 8
#define TT 4096
#define FF 256
#define BT 32768   // BB*TT

typedef unsigned short u16;
typedef __attribute__((ext_vector_type(8))) short short8;
typedef __attribute__((ext_vector_type(4))) float f32x4;
typedef __attribute__((ext_vector_type(4))) unsigned int u32x4;

static __device__ __forceinline__ float bf2f(u16 u) {
    union { unsigned int i; float f; } v; v.i = ((unsigned int)u) << 16; return v.f;
}
static __device__ __forceinline__ u16 f2bf(float f) {
    union { float f; unsigned int i; } v; v.f = f;
    unsigned int x = v.i;
    return (u16)((x + 0x7fffu + ((x >> 16) & 1u)) >> 16);  // RNE
}

typedef const __attribute__((address_space(1))) void gvoid_t;
typedef __attribute__((address_space(3))) void svoid_t;

// ---------------------------------------------------------------------------
// prep: ew = exp(w) (row-max cancels in num/den — verified R12), x -> bf16,
// wq/wo -> bf16, (wk,wv) -> interleaved wkv. One elementwise launch.
// v4-items: [0, 4194304) w | [, +2097152) x | [, +49152) weights
// ---------------------------------------------------------------------------
__global__ __launch_bounds__(256) void prep_kernel(const float* __restrict__ w,
                                                   const float* __restrict__ x,
                                                   const float* __restrict__ wq,
                                                   const float* __restrict__ wo,
                                                   const float* __restrict__ wk,
                                                   const float* __restrict__ wv,
                                                   u16* __restrict__ ew,
                                                   u16* __restrict__ xbf,
                                                   u16* __restrict__ wqb,
                                                   u16* __restrict__ wob,
                                                   u16* __restrict__ wkv) {
    int i = blockIdx.x * 256 + threadIdx.x;
    if (i < 4194304) {
        int idx = i * 4;
        f32x4 v = *(const f32x4*)(w + idx);
        uint2 pk;
        pk.x = (unsigned int)f2bf(expf(v[0])) | ((unsigned int)f2bf(expf(v[1])) << 16);
        pk.y = (unsigned int)f2bf(expf(v[2])) | ((unsigned int)f2bf(expf(v[3])) << 16);
        *(uint2*)(ew + idx) = pk;
        return;
    }
    int j = i - 4194304;
    if (j < 2097152) {
        int idx = j * 4;
        f32x4 v = *(const f32x4*)(x + idx);
        uint2 pk;
        pk.x = (unsigned int)f2bf(v[0]) | ((unsigned int)f2bf(v[1]) << 16);
        pk.y = (unsigned int)f2bf(v[2]) | ((unsigned int)f2bf(v[3]) << 16);
        *(uint2*)(xbf + idx) = pk;
        return;
    }
    int k = j - 2097152;           // [0, 49152)
    int which = k >> 14, kk = k & 16383;
    int idx = kk * 4;
    if (which == 0) {
        f32x4 v = *(const f32x4*)(wq + idx);
        uint2 pk;
        pk.x = (unsigned int)f2bf(v[0]) | ((unsigned int)f2bf(v[1]) << 16);
        pk.y = (unsigned int)f2bf(v[2]) | ((unsigned int)f2bf(v[3]) << 16);
        *(uint2*)(wqb + idx) = pk;
    } else if (which == 1) {
        f32x4 v = *(const f32x4*)(wo + idx);
        uint2 pk;
        pk.x = (unsigned int)f2bf(v[0]) | ((unsigned int)f2bf(v[1]) << 16);
        pk.y = (unsigned int)f2bf(v[2]) | ((unsigned int)f2bf(v[3]) << 16);
        *(uint2*)(wob + idx) = pk;
    } else {
        int f = idx >> 8, c = idx & 255;
        f32x4 a = *(const f32x4*)(wk + idx);
        f32x4 b = *(const f32x4*)(wv + idx);
        uint2 pa, pb;
        pa.x = (unsigned int)f2bf(a[0]) | ((unsigned int)f2bf(a[1]) << 16);
        pa.y = (unsigned int)f2bf(a[2]) | ((unsigned int)f2bf(a[3]) << 16);
        pb.x = (unsigned int)f2bf(b[0]) | ((unsigned int)f2bf(b[1]) << 16);
        pb.y = (unsigned int)f2bf(b[2]) | ((unsigned int)f2bf(b[3]) << 16);
        *(uint2*)(wkv + (size_t)(2 * f) * 256 + c) = pa;
        *(uint2*)(wkv + (size_t)(2 * f + 1) * 256 + c) = pb;
    }
}

// ---------------------------------------------------------------------------
// Small NT GEMM (m97 structure) + 64B-row XOR swizzle (R11-verified).
// MODE 0: f32 out; 1: sigmoid->bf16
// ---------------------------------------------------------------------------
template <int MODE>
__global__ __launch_bounds__(256) void gemm_nt(const u16* __restrict__ A,
                                               const u16* __restrict__ Bm,
                                               const float* __restrict__ bias,
                                               void* __restrict__ Call,
                                               int M, int N, int K) {
    __shared__ u16 As[128 * 32];
    __shared__ u16 Bs[128 * 32];

    int tid = threadIdx.x;
    int lane = tid & 63;
    int w = tid >> 6;
    int wr = w >> 1, wc = w & 1;
    int fr = lane & 15, kg = lane >> 4;

    f32x4 acc[4][4];
#pragma unroll
    for (int m = 0; m < 4; ++m)
#pragma unroll
        for (int n = 0; n < 4; ++n) acc[m][n] = (f32x4){0.f, 0.f, 0.f, 0.f};

    int bm = blockIdx.x, bn = blockIdx.y;
    int nk = K >> 5;

    int srow = tid >> 2;
    int schunk = ((tid & 3) ^ ((tid >> 3) & 3)) << 3;   // inverse-swizzled source col
    const u16* aBase = A + (size_t)(bm * 128 + srow) * K + schunk;
    const u16* bBase = Bm + (size_t)(bn * 128 + srow) * K + schunk;
    size_t half = (size_t)64 * K;

    int xsw = (kg * 8) ^ (((fr >> 1) & 3) << 3);        // swizzled read col (elems)

    for (int kt = 0; kt < nk; ++kt) {
        __syncthreads();
        int ko = kt << 5;
        __builtin_amdgcn_global_load_lds((gvoid_t*)(aBase + ko), (svoid_t*)&As[tid * 8], 16, 0, 0);
        __builtin_amdgcn_global_load_lds((gvoid_t*)(aBase + half + ko), (svoid_t*)&As[2048 + tid * 8], 16, 0, 0);
        __builtin_amdgcn_global_load_lds((gvoid_t*)(bBase + ko), (svoid_t*)&Bs[tid * 8], 16, 0, 0);
        __builtin_amdgcn_global_load_lds((gvoid_t*)(bBase + half + ko), (svoid_t*)&Bs[2048 + tid * 8], 16, 0, 0);
        __syncthreads();

        short8 af[4], bfr[4];
#pragma unroll
        for (int m = 0; m < 4; ++m)
            af[m] = *(const short8*)&As[(wr * 64 + m * 16 + fr) * 32 + xsw];
#pragma unroll
        for (int n = 0; n < 4; ++n)
            bfr[n] = *(const short8*)&Bs[(wc * 64 + n * 16 + fr) * 32 + xsw];
#pragma unroll
        for (int m = 0; m < 4; ++m)
#pragma unroll
            for (int n = 0; n < 4; ++n)
                acc[m][n] = __builtin_amdgcn_mfma_f32_16x16x32_bf16(af[m], bfr[n], acc[m][n], 0, 0, 0);
    }

    int row0 = bm * 128 + wr * 64;
    int col0 = bn * 128 + wc * 64;
#pragma unroll
    for (int n = 0; n < 4; ++n) {
        int col = col0 + n * 16 + fr;
        float bv = bias ? bias[col] : 0.0f;
#pragma unroll
        for (int m = 0; m < 4; ++m) {
            int rbase = row0 + m * 16 + kg * 4;
#pragma unroll
            for (int i = 0; i < 4; ++i) {
                float val = acc[m][n][i] + bv;
                size_t idx = (size_t)(rbase + i) * N + col;
                if (MODE == 0)
                    ((float*)Call)[idx] = val;
                else
                    ((u16*)Call)[idx] = f2bf(1.0f / (1.0f + expf(-val)));
            }
        }
    }
}

// ---------------------------------------------------------------------------
// Fused K/V projection + Mt build (R11, unchanged — feature-dim max REQUIRED:
// it varies over the summation index s and does not cancel in num/den).
// ---------------------------------------------------------------------------
__global__ __launch_bounds__(512) void kv_mt_kernel(const u16* __restrict__ xbf,
                                                    const u16* __restrict__ wkv,
                                                    const float* __restrict__ bk,
                                                    const float* __restrict__ bv,
                                                    u16* __restrict__ mt) {
    __shared__ u16 As[128 * 32];     // 8 KB
    __shared__ u16 Bs[512 * 32];     // 32 KB
    __shared__ float rmax4[128][4];  // 2 KB

    int tid = threadIdx.x;
    int lane = tid & 63, wid = tid >> 6;
    int fr = lane & 15, kg = lane >> 4;
    int wr = wid >> 2, wc = wid & 3;
    int row0g = blockIdx.x * 128;

    f32x4 acc[4][8];
#pragma unroll
    for (int m = 0; m < 4; ++m)
#pragma unroll
        for (int n = 0; n < 8; ++n) acc[m][n] = (f32x4){0.f, 0.f, 0.f, 0.f};

    int scol = ((tid & 3) ^ ((tid >> 3) & 3)) << 3;   // inverse-swizzled source col
    const u16* aSrc = xbf + (size_t)(row0g + (tid >> 2)) * 256 + scol;
    const u16* bSrc = wkv + (size_t)(tid >> 2) * 256 + scol;
    int xsw = (kg * 8) ^ (((fr >> 1) & 3) << 3);      // swizzled read col (elems)

    for (int ks = 0; ks < 8; ++ks) {
        __syncthreads();
        __builtin_amdgcn_global_load_lds((gvoid_t*)(aSrc + ks * 32), (svoid_t*)&As[tid * 8], 16, 0, 0);
#pragma unroll
        for (int c = 0; c < 4; ++c)
            __builtin_amdgcn_global_load_lds((gvoid_t*)(bSrc + (size_t)c * 128 * 256 + ks * 32),
                                             (svoid_t*)&Bs[c * 4096 + tid * 8], 16, 0, 0);
        __syncthreads();

        short8 af[4], bfr[8];
#pragma unroll
        for (int m = 0; m < 4; ++m)
            af[m] = *(const short8*)&As[(wr * 64 + m * 16 + fr) * 32 + xsw];
#pragma unroll
        for (int n = 0; n < 8; ++n)
            bfr[n] = *(const short8*)&Bs[(wc * 128 + n * 16 + fr) * 32 + xsw];
#pragma unroll
        for (int m = 0; m < 4; ++m)
#pragma unroll
            for (int n = 0; n < 8; ++n)
                acc[m][n] = __builtin_amdgcn_mfma_f32_16x16x32_bf16(af[m], bfr[n], acc[m][n], 0, 0, 0);
    }

    int par = fr & 1;   // 0: K (den), 1: V (num)
#pragma unroll
    for (int n = 0; n < 8; ++n) {
        int col = wc * 128 + n * 16 + fr;
        int f = col >> 1;
        float bvv = par ? bv[f] : bk[f];
#pragma unroll
        for (int m = 0; m < 4; ++m)
#pragma unroll
            for (int i = 0; i < 4; ++i) acc[m][n][i] += bvv;
    }

    float rmax[4][4];
#pragma unroll
    for (int m = 0; m < 4; ++m)
#pragma unroll
        for (int i = 0; i < 4; ++i) {
            float mx = -1e30f;
#pragma unroll
            for (int n = 0; n < 8; ++n) mx = fmaxf(mx, par ? -1e30f : acc[m][n][i]);
            mx = fmaxf(mx, __shfl_xor(mx, 2));
            mx = fmaxf(mx, __shfl_xor(mx, 4));
            mx = fmaxf(mx, __shfl_xor(mx, 8));
            mx = fmaxf(mx, __shfl_xor(mx, 1));
            rmax[m][i] = mx;
        }
    if (fr == 0) {
#pragma unroll
        for (int m = 0; m < 4; ++m)
#pragma unroll
            for (int i = 0; i < 4; ++i)
                rmax4[wr * 64 + m * 16 + kg * 4 + i][wc] = rmax[m][i];
    }
    __syncthreads();
#pragma unroll
    for (int m = 0; m < 4; ++m)
#pragma unroll
        for (int i = 0; i < 4; ++i) {
            f32x4 r4 = *(const f32x4*)rmax4[wr * 64 + m * 16 + kg * 4 + i];
            rmax[m][i] = fmaxf(fmaxf(r4[0], r4[1]), fmaxf(r4[2], r4[3]));
        }

    int b = row0g >> 12;
    int tcb = (row0g & 4095) + wr * 64;
#pragma unroll
    for (int n = 0; n < 8; ++n) {
        int col = wc * 128 + n * 16 + fr;
        int f = col >> 1;
        size_t rowmt = (size_t)(b * 512 + 2 * f + (par ? 0 : 1));
#pragma unroll
        for (int m = 0; m < 4; ++m) {
            int tc = tcb + m * 16 + kg * 4;
            u16 o[4];
#pragma unroll
            for (int i = 0; i < 4; ++i) {
                float v = acc[m][n][i];
                float ek = expf(v - rmax[m][i]);
                float ekx = __shfl_xor(ek, 1);
                float outv = par ? (ekx * v) : ek;
                o[i] = f2bf(outv);
            }
            uint2 pk;
            pk.x = (unsigned int)o[0] | ((unsigned int)o[1] << 16);
            pk.y = (unsigned int)o[2] | ((unsigned int)o[3] << 16);
            *(uint2*)(mt + rowmt * TT + tc) = pk;
        }
    }
}

// ---------------------------------------------------------------------------
// Big 4096^3 NT GEMM — EXACT R6/R11 (measured 115.8 us, best of 7 structural
// variants this session). BK=64, 2 LDS buffers, ONE barrier + vmcnt(0) per
// tile, stage after reads, XOR-swizzled 128B rows, setprio, fused all-lane
// AFT epilogue. Do not touch.
// ---------------------------------------------------------------------------
#define GLDS(src, eoff) \
    __builtin_amdgcn_global_load_lds((gvoid_t*)(src), (svoid_t*)&L[eoff], 16, 0, 0)

#define STAGE8(P_, KS_) do {                                                   \
    _Pragma("unroll")                                                          \
    for (int i_ = 0; i_ < 4; ++i_) {                                           \
        GLDS(sA + (size_t)i_ * 64 * 4096 + (KS_) * 64,                         \
             (P_) * 16384 + i_ * 4096 + dst);                                  \
        GLDS(sB + (size_t)i_ * 64 * 4096 + (KS_) * 64,                         \
             32768 + (P_) * 16384 + i_ * 4096 + dst);                          \
    }                                                                          \
} while (0)

__global__ __launch_bounds__(512, 2) void gemm256_nt(const u16* __restrict__ A,
                                                     const u16* __restrict__ B,
                                                     const u16* __restrict__ qsig,
                                                     u16* __restrict__ yt) {
    __shared__ u16 L[65536];   // 128 KiB
    const int K = 4096;
    int tid = threadIdx.x;
    int lane = tid & 63, wid = tid >> 6;
    int fr = lane & 15, kg = lane >> 4;
    int wr = wid >> 2, wc = wid & 3;
    int bm = blockIdx.x, bn = blockIdx.y;
    const char* LB = (const char*)L;

    // swizzled in-row byte offsets for kk=0,1
    int x0 = (kg * 16) ^ ((fr & 7) << 4);
    int x1 = (64 + kg * 16) ^ ((fr & 7) << 4);
    int arow = (wr * 128 + fr) * 128;   // + mf*2048
    int brow = (wc * 64 + fr) * 128;    // + nf*2048

    // staging source (inverse swizzle), dest = linear tid*16B per issue
    int scol = ((tid & 7) * 8) ^ (((tid >> 3) & 7) << 3);
    const u16* sA = A + (size_t)(bm * 256 + (tid >> 3)) * K + scol;
    const u16* sB = B + (size_t)(bn * 256 + (tid >> 3)) * K + scol;
    int dst = tid * 8;   // elems

    f32x4 acc[8][4];
#pragma unroll
    for (int m = 0; m < 8; ++m)
#pragma unroll
        for (int n = 0; n < 4; ++n) acc[m][n] = (f32x4){0.f, 0.f, 0.f, 0.f};

    // prologue: stage tile 0 -> buf 0
    STAGE8(0, 0);
    asm volatile("s_waitcnt vmcnt(0)" ::: "memory");
    __builtin_amdgcn_sched_barrier(0);
    __builtin_amdgcn_s_barrier();

#pragma unroll 1
    for (int t = 0; t < 64; ++t) {
        int p = t & 1;
        const char* abase = LB + p * 32768;
        const char* bbase = LB + 65536 + p * 32768;

        short8 bfr[4][2], af[4][2];
#pragma unroll
        for (int nf = 0; nf < 4; ++nf) {
            const char* rb = bbase + brow + nf * 2048;
            bfr[nf][0] = *(const short8*)(rb + x0);
            bfr[nf][1] = *(const short8*)(rb + x1);
        }
#pragma unroll
        for (int mf = 0; mf < 4; ++mf) {
            const char* rb = abase + arow + mf * 2048;
            af[mf][0] = *(const short8*)(rb + x0);
            af[mf][1] = *(const short8*)(rb + x1);
        }
        int ks = (t + 1 < 64) ? t + 1 : 0;
        STAGE8(p ^ 1, ks);
        asm volatile("s_waitcnt lgkmcnt(0)" ::: "memory");
        __builtin_amdgcn_sched_barrier(0);
        __builtin_amdgcn_s_setprio(1);
#pragma unroll
        for (int mf = 0; mf < 4; ++mf)
#pragma unroll
            for (int nf = 0; nf < 4; ++nf) {
                acc[mf][nf] = __builtin_amdgcn_mfma_f32_16x16x32_bf16(af[mf][0], bfr[nf][0], acc[mf][nf], 0, 0, 0);
                acc[mf][nf] = __builtin_amdgcn_mfma_f32_16x16x32_bf16(af[mf][1], bfr[nf][1], acc[mf][nf], 0, 0, 0);
            }
        __builtin_amdgcn_s_setprio(0);
        // second half: rows 4..7
#pragma unroll
        for (int mf = 0; mf < 4; ++mf) {
            const char* rb = abase + arow + (mf + 4) * 2048;
            af[mf][0] = *(const short8*)(rb + x0);
            af[mf][1] = *(const short8*)(rb + x1);
        }
        asm volatile("s_waitcnt lgkmcnt(0)" ::: "memory");
        __builtin_amdgcn_sched_barrier(0);
        __builtin_amdgcn_s_setprio(1);
#pragma unroll
        for (int mf = 0; mf < 4; ++mf)
#pragma unroll
            for (int nf = 0; nf < 4; ++nf) {
                acc[mf + 4][nf] = __builtin_amdgcn_mfma_f32_16x16x32_bf16(af[mf][0], bfr[nf][0], acc[mf + 4][nf], 0, 0, 0);
                acc[mf + 4][nf] = __builtin_amdgcn_mfma_f32_16x16x32_bf16(af[mf][1], bfr[nf][1], acc[mf + 4][nf], 0, 0, 0);
            }
        __builtin_amdgcn_s_setprio(0);
        asm volatile("s_waitcnt vmcnt(0)" ::: "memory");
        __builtin_amdgcn_sched_barrier(0);
        __builtin_amdgcn_s_barrier();
    }

    // fused AFT epilogue: all lanes productive. Even fr: i 0..1; odd fr: i 2..3.
    int colgb = bn * 256 + wc * 64;
    int row0 = bm * 256 + wr * 128;
    int par = fr & 1;
#pragma unroll
    for (int n = 0; n < 4; ++n) {
        int colg = colgb + n * 16 + fr;
        int b = colg >> 9;
        int f = (colg & 511) >> 1;
#pragma unroll
        for (int m = 0; m < 8; ++m) {
            int tr0 = row0 + m * 16 + kg * 4;
            float v0 = acc[m][n][0], v1 = acc[m][n][1];
            float v2 = acc[m][n][2], v3 = acc[m][n][3];
            float o0 = __shfl_xor(v0, 1), o1 = __shfl_xor(v1, 1);
            float o2 = __shfl_xor(v2, 1), o3 = __shfl_xor(v3, 1);
            // even lane: num = own, den = other; odd: num = other, den = own
            float nA = par ? o2 : v0, dA = par ? v2 : o0;   // i = par?2:0
            float nB = par ? o3 : v1, dB = par ? v3 : o1;   // i = par?3:1
            int iA = par ? 2 : 0;
            size_t idxA = ((size_t)(b * 4096 + tr0 + iA) << 8) + f;
            size_t idxB = idxA + 256;
            float qA = bf2f(qsig[idxA]);
            float qB = bf2f(qsig[idxB]);
            yt[idxA] = f2bf(qA * nA * __builtin_amdgcn_rcpf(dA));
            yt[idxB] = f2bf(qB * nB * __builtin_amdgcn_rcpf(dB));
        }
    }
}

// ---------------------------------------------------------------------------
extern "C" void kernel_launch(void* const* d_in, const int* in_sizes, int n_in,
                              void* d_out, int out_size, void* d_ws, size_t ws_size,
                              hipStream_t stream) {
    const float* x  = (const float*)d_in[0];
    const float* wq = (const float*)d_in[1];
    const float* bq = (const float*)d_in[2];
    const float* wk = (const float*)d_in[3];
    const float* bk = (const float*)d_in[4];
    const float* wv = (const float*)d_in[5];
    const float* bv = (const float*)d_in[6];
    const float* w  = (const float*)d_in[7];
    const float* wo = (const float*)d_in[8];
    const float* bo = (const float*)d_in[9];

    char* p = (char*)d_ws;
    u16* expw = (u16*)p; p += (size_t)TT * TT * 2;        // 32 MiB
    u16* xbf  = (u16*)p; p += (size_t)BT * FF * 2;        // 16 MiB (reused as yt)
    u16* wqb  = (u16*)p; p += (size_t)FF * FF * 2;
    u16* wob  = (u16*)p; p += (size_t)FF * FF * 2;
    u16* wkv  = (u16*)p; p += (size_t)2 * FF * FF * 2;    // interleaved [512][256]
    u16* qsig = (u16*)p; p += (size_t)BT * FF * 2;        // 16 MiB
    u16* mt   = (u16*)p; p += (size_t)BB * 512 * TT * 2;  // 32 MiB (flat [4096][T])
    u16* yt = xbf;

    // single prep launch: exp(w) + all casts (4194304+2097152+49152 = 6340608 v4-items)
    prep_kernel<<<24768, 256, 0, stream>>>(w, x, wq, wo, wk, wv,
                                           expw, xbf, wqb, wob, wkv);

    dim3 gp(BT / 128, FF / 128, 1);
    gemm_nt<1><<<gp, 256, 0, stream>>>(xbf, wqb, bq, qsig, BT, FF, FF);

    kv_mt_kernel<<<BT / 128, 512, 0, stream>>>(xbf, wkv, bk, bv, mt);

    // big GEMM + fused AFT epilogue (exact R6 loop)
    gemm256_nt<<<dim3(16, 16), 512, 0, stream>>>(expw, mt, qsig, yt);

    gemm_nt<0><<<gp, 256, 0, stream>>>(yt, wob, bo, (float*)d_out, BT, FF, FF);
}